// Round 4
// baseline (748.840 us; speedup 1.0000x reference)
//
#include <hip/hip_runtime.h>

#define BT    2048
#define HDIM  1024
#define VDIM  32000
#define NSEQ  4
#define BETA  0.1f
#define IGNORE_IDX (-100)

typedef __attribute__((ext_vector_type(8))) short bf16x8;
typedef __attribute__((ext_vector_type(8))) unsigned short u16x8;
typedef __attribute__((ext_vector_type(4))) float f32x4;

// ---------------- ws layout ----------------
// floats: [0..4096) ws_se ([2][BT])  [4096..8192) ws_tg ([2][BT])  -> 32768 bytes
// bytes 32768+: bf16 Xbf, Xrbf, Wbf, Wrbf (element offsets)
#define WS_BF_BYTE  32768
#define XBF_OFF     0
#define XRBF_OFF    (BT * HDIM)
#define WBF_OFF     (2 * BT * HDIM)
#define WRBF_OFF    (2 * BT * HDIM + VDIM * HDIM)
#define CVT_TOTAL   (2 * BT * HDIM + 2 * VDIM * HDIM)   // 69,730,304 elems
#define WS_NEED     ((size_t)WS_BF_BYTE + (size_t)CVT_TOTAL * 2)

__device__ __forceinline__ unsigned short f2bf_rne(float f) {
  unsigned int u = __builtin_bit_cast(unsigned int, f);
  u += 0x7fffu + ((u >> 16) & 1u);
  return (unsigned short)(u >> 16);
}

__device__ __forceinline__ u16x8 cvt8(float4 a, float4 b) {
  u16x8 v;
  v[0] = f2bf_rne(a.x); v[1] = f2bf_rne(a.y); v[2] = f2bf_rne(a.z); v[3] = f2bf_rne(a.w);
  v[4] = f2bf_rne(b.x); v[5] = f2bf_rne(b.y); v[6] = f2bf_rne(b.z); v[7] = f2bf_rne(b.w);
  return v;
}

// fp32 -> bf16 conversion (16 elems/thread) + fused ws_se/ws_tg zeroing.
// NOTE: zero exactly 4*BT floats (se 2*BT + tg 2*BT). Round-3 bug: 2x overrun
// stomped the first bf16 X rows (race with their conversion).
__global__ __launch_bounds__(256) void kto_convert(
    const float* __restrict__ X, const float* __restrict__ Xr,
    const float* __restrict__ W, const float* __restrict__ Wr,
    unsigned short* __restrict__ bf, float* __restrict__ ws_zero)
{
  if (blockIdx.x == 0) {
    for (int i = threadIdx.x; i < 4 * BT; i += 256) ws_zero[i] = 0.0f;
  }
  size_t gid = ((size_t)blockIdx.x * 256 + threadIdx.x) * 16;
  if (gid >= (size_t)CVT_TOTAL) return;
  const float* src; size_t off;
  if (gid < (size_t)XRBF_OFF)      { src = X;  off = gid; }
  else if (gid < (size_t)WBF_OFF)  { src = Xr; off = gid - XRBF_OFF; }
  else if (gid < (size_t)WRBF_OFF) { src = W;  off = gid - WBF_OFF; }
  else                             { src = Wr; off = gid - WRBF_OFF; }
  const float4* p = (const float4*)(src + off);
  float4 a = p[0], b = p[1], c = p[2], d = p[3];
  *(u16x8*)(bf + gid)     = cvt8(a, b);
  *(u16x8*)(bf + gid + 8) = cvt8(c, d);
}

#define GLD16(g, l) __builtin_amdgcn_global_load_lds( \
    (const __attribute__((address_space(1))) unsigned int*)(g), \
    (__attribute__((address_space(3))) unsigned int*)(l), 16, 0, 0)

// BK=64 fused GEMM + logsumexp partials, XCD-swizzled 1-D grid of 8000.
// XCD k (b&7): model = k>>2; quadrant (x-half, y-half) = (k&1, (k>>1)&1).
// Per XCD: 8 x-tiles x 125 y-strips = 1000 blocks, j = b>>3.
__global__ __launch_bounds__(256) void kto_lse_gemm3(
    const unsigned short* __restrict__ bf,
    const float* __restrict__ Bp, const float* __restrict__ Br,
    const int* __restrict__ target,
    float* __restrict__ ws_se, float* __restrict__ ws_tg)
{
  const int b    = blockIdx.x;
  const int xcd  = b & 7;
  const int j    = b >> 3;
  const int model = xcd >> 2;
  const int k2   = xcd & 3;
  const int xt   = (k2 & 1) * 8 + (j & 7);           // 0..15
  const int yt   = ((k2 >> 1) & 1) * 125 + (j >> 3); // 0..249

  const unsigned short* __restrict__ Xb = bf + (model ? XRBF_OFF : XBF_OFF);
  const unsigned short* __restrict__ Wb = bf + (model ? WRBF_OFF : WBF_OFF);
  const float* __restrict__ Bv = model ? Br : Bp;

  const int mBase = xt * 128;
  const int nBase = yt * 128;

  __shared__ unsigned short Asm[128 * 64];  // 16 KB, 128 B rows, no pad
  __shared__ unsigned short Bsm[128 * 64];  // 16 KB

  const int tid  = threadIdx.x;
  const int wave = tid >> 6;
  const int lane = tid & 63;
  const int q    = lane >> 4;
  const int c    = lane & 15;
  const int mW   = (wave >> 1) * 64;
  const int nW   = (wave & 1) * 64;

  // staging: 16 segments of 1 KB each for A and B (8 rows x 128 B).
  // lane l covers (row = l>>3, slot = l&7) holding global chunk (l&7)^(row&7).
  const int lrow = lane >> 3;
  const int lchk = (lane & 7) ^ (lrow & 7);

  const char* gsrcA[4]; const char* gsrcB[4];
  unsigned short* ldstA[4]; unsigned short* ldstB[4];
  #pragma unroll
  for (int s = 0; s < 4; ++s) {
    const int seg = wave * 4 + s;                 // 0..15
    const int rowA = mBase + seg * 8 + lrow;
    const int rowB = nBase + seg * 8 + lrow;
    gsrcA[s] = (const char*)Xb + (size_t)rowA * (HDIM * 2) + lchk * 16;
    gsrcB[s] = (const char*)Wb + (size_t)rowB * (HDIM * 2) + lchk * 16;
    ldstA[s] = &Asm[seg * 512];
    ldstB[s] = &Bsm[seg * 512];
  }

  f32x4 acc[4][4] = {};

  for (int kt = 0; kt < HDIM / 64; ++kt) {        // 16 stages
    __syncthreads();
    const size_t kb = (size_t)kt * 128;           // 64 bf16 = 128 B
    #pragma unroll
    for (int s = 0; s < 4; ++s) {
      GLD16(gsrcA[s] + kb, ldstA[s]);
      GLD16(gsrcB[s] + kb, ldstB[s]);
    }
    __syncthreads();

    #pragma unroll
    for (int h = 0; h < 2; ++h) {
      // global chunk for k-half h, quad q: chunk = h*4+q; LDS slot = chunk ^ (row&7)
      bf16x8 afr[4], bfr[4];
      #pragma unroll
      for (int mi = 0; mi < 4; ++mi) {
        const int row = mW + mi * 16 + c;
        const int slot = ((h << 2) | q) ^ (row & 7);
        afr[mi] = *(const bf16x8*)&Asm[row * 64 + slot * 8];
      }
      #pragma unroll
      for (int ni = 0; ni < 4; ++ni) {
        const int row = nW + ni * 16 + c;
        const int slot = ((h << 2) | q) ^ (row & 7);
        bfr[ni] = *(const bf16x8*)&Bsm[row * 64 + slot * 8];
      }
      #pragma unroll
      for (int mi = 0; mi < 4; ++mi)
        #pragma unroll
        for (int ni = 0; ni < 4; ++ni)
          acc[mi][ni] = __builtin_amdgcn_mfma_f32_16x16x32_bf16(afr[mi], bfr[ni], acc[mi][ni], 0, 0, 0);
    }
  }

  // epilogue: bias + exp + target pick (registers only)
  float se_acc[4][4] = {};
  float tg_acc[4][4] = {};
  int tgt_idx[4][4];
  #pragma unroll
  for (int mi = 0; mi < 4; ++mi)
    #pragma unroll
    for (int r = 0; r < 4; ++r)
      tgt_idx[mi][r] = target[mBase + mW + mi * 16 + q * 4 + r];

  #pragma unroll
  for (int ni = 0; ni < 4; ++ni) {
    const int col = nBase + nW + ni * 16 + c;
    const float bv = Bv[col];
    #pragma unroll
    for (int mi = 0; mi < 4; ++mi)
      #pragma unroll
      for (int r = 0; r < 4; ++r) {
        float logit = acc[mi][ni][r] + bv;
        se_acc[mi][r] += __expf(logit);
        if (tgt_idx[mi][r] == col) tg_acc[mi][r] += logit;
      }
  }

  // quad (16-lane) butterfly, one atomic pair per row spread across lanes
  #pragma unroll
  for (int mi = 0; mi < 4; ++mi)
    #pragma unroll
    for (int r = 0; r < 4; ++r) {
      float s = se_acc[mi][r];
      float t = tg_acc[mi][r];
      #pragma unroll
      for (int off = 1; off < 16; off <<= 1) {
        s += __shfl_xor(s, off, 64);
        t += __shfl_xor(t, off, 64);
      }
      if (c == ((mi << 2) | r)) {
        const int row = mBase + mW + mi * 16 + q * 4 + r;
        atomicAdd(&ws_se[model * BT + row], s);
        atomicAdd(&ws_tg[model * BT + row], t);
      }
    }
}

// ---------------- fallback (round-1 style, used only if ws too small) ----------------
#define SLDK 40

__global__ __launch_bounds__(256) void kto_zero_ws(float* p) {
  p[blockIdx.x * 256 + threadIdx.x] = 0.0f;
}

__global__ __launch_bounds__(256) void kto_lse_gemm_slow(
    const float* __restrict__ Xp, const float* __restrict__ Wp, const float* __restrict__ Bp,
    const float* __restrict__ Xr, const float* __restrict__ Wr, const float* __restrict__ Br,
    const int* __restrict__ target, float* __restrict__ ws_se, float* __restrict__ ws_tg)
{
  const int model = blockIdx.z;
  const float* __restrict__ X  = model ? Xr : Xp;
  const float* __restrict__ W  = model ? Wr : Wp;
  const float* __restrict__ Bv = model ? Br : Bp;

  __shared__ unsigned short Asm[128][SLDK];
  __shared__ unsigned short Bsm[128][SLDK];

  const int tid  = threadIdx.x;
  const int wave = tid >> 6;
  const int lane = tid & 63;
  const int q    = lane >> 4;
  const int c    = lane & 15;
  const int mW   = (wave >> 1) * 64;
  const int nW   = (wave & 1) * 64;
  const int mBase = blockIdx.x * 128;
  const int vBase = blockIdx.y * 1280;

  const int srow = tid >> 1;
  const int scol = (tid & 1) << 4;

  int tgt_idx[4][4];
  #pragma unroll
  for (int mi = 0; mi < 4; ++mi)
    #pragma unroll
    for (int r = 0; r < 4; ++r)
      tgt_idx[mi][r] = target[mBase + mW + mi * 16 + q * 4 + r];

  float se_acc[4][4] = {};
  float tg_acc[4][4] = {};

  for (int it = 0; it < 10; ++it) {
    const int nIterBase = vBase + it * 128;
    f32x4 acc[4][4] = {};
    for (int kt = 0; kt < HDIM / 32; ++kt) {
      __syncthreads();
      {
        const float4* a4 = (const float4*)(X + (size_t)(mBase + srow) * HDIM + kt * 32 + scol);
        float4 a0 = a4[0], a1 = a4[1], a2 = a4[2], a3 = a4[3];
        const float4* b4 = (const float4*)(W + (size_t)(nIterBase + srow) * HDIM + kt * 32 + scol);
        float4 b0 = b4[0], b1 = b4[1], b2 = b4[2], b3 = b4[3];
        *(u16x8*)&Asm[srow][scol]     = cvt8(a0, a1);
        *(u16x8*)&Asm[srow][scol + 8] = cvt8(a2, a3);
        *(u16x8*)&Bsm[srow][scol]     = cvt8(b0, b1);
        *(u16x8*)&Bsm[srow][scol + 8] = cvt8(b2, b3);
      }
      __syncthreads();
      bf16x8 afr[4], bfr[4];
      #pragma unroll
      for (int mi = 0; mi < 4; ++mi)
        afr[mi] = *(const bf16x8*)&Asm[mW + mi * 16 + c][q * 8];
      #pragma unroll
      for (int ni = 0; ni < 4; ++ni)
        bfr[ni] = *(const bf16x8*)&Bsm[nW + ni * 16 + c][q * 8];
      #pragma unroll
      for (int mi = 0; mi < 4; ++mi)
        #pragma unroll
        for (int ni = 0; ni < 4; ++ni)
          acc[mi][ni] = __builtin_amdgcn_mfma_f32_16x16x32_bf16(afr[mi], bfr[ni], acc[mi][ni], 0, 0, 0);
    }
    #pragma unroll
    for (int ni = 0; ni < 4; ++ni) {
      const int col = nIterBase + nW + ni * 16 + c;
      const float bv = Bv[col];
      #pragma unroll
      for (int mi = 0; mi < 4; ++mi)
        #pragma unroll
        for (int r = 0; r < 4; ++r) {
          float logit = acc[mi][ni][r] + bv;
          se_acc[mi][r] += __expf(logit);
          if (tgt_idx[mi][r] == col) tg_acc[mi][r] += logit;
        }
    }
  }
  #pragma unroll
  for (int mi = 0; mi < 4; ++mi)
    #pragma unroll
    for (int r = 0; r < 4; ++r) {
      float s = se_acc[mi][r];
      float t = tg_acc[mi][r];
      #pragma unroll
      for (int off = 1; off < 16; off <<= 1) {
        s += __shfl_xor(s, off, 64);
        t += __shfl_xor(t, off, 64);
      }
      if (c == 0) {
        const int row = mBase + mW + mi * 16 + q * 4 + r;
        atomicAdd(&ws_se[model * BT + row], s);
        atomicAdd(&ws_tg[model * BT + row], t);
      }
    }
}

__global__ __launch_bounds__(256) void kto_finalize(
    const float* __restrict__ ws_se, const float* __restrict__ ws_tg,
    const int* __restrict__ target, const int* __restrict__ pref,
    const float* __restrict__ kl, float* __restrict__ out)
{
  __shared__ float lr[NSEQ];
  const int tid = threadIdx.x;
  if (tid < NSEQ) lr[tid] = 0.0f;
  __syncthreads();
  for (int t = tid; t < BT; t += 256) {
    float d = 0.0f;
    if (target[t] != IGNORE_IDX) {
      float lp_p = ws_tg[t]      - __logf(ws_se[t]);
      float lp_r = ws_tg[BT + t] - __logf(ws_se[BT + t]);
      d = lp_p - lp_r;
    }
    atomicAdd(&lr[t >> 9], d);
  }
  __syncthreads();
  if (tid == 0) {
    float loss = 0.f, ch = 0.f, rj = 0.f;
    const float klv = kl[0];
    for (int b = 0; b < NSEQ; ++b) {
      float logratio = lr[b];
      bool p = pref[b] != 0;
      float mult = p ? 1.0f : -1.0f;
      float z = BETA * (logratio - klv) * mult;
      float sig = 1.0f / (1.0f + __expf(-z));
      loss += 1.0f - sig;
      float rw = BETA * logratio;
      if (p) ch += rw; else rj += rw;
    }
    out[0] = loss / (float)BT;
    out[1] = ch;
    out[2] = rj;
  }
}

extern "C" void kernel_launch(void* const* d_in, const int* in_sizes, int n_in,
                              void* d_out, int out_size, void* d_ws, size_t ws_size,
                              hipStream_t stream) {
  (void)in_sizes; (void)n_in; (void)out_size;
  const float* X    = (const float*)d_in[0];
  const float* W    = (const float*)d_in[1];
  const int*   tgt  = (const int*)d_in[2];
  const float* bias = (const float*)d_in[3];
  const int*   pref = (const int*)d_in[4];
  const float* Xr   = (const float*)d_in[5];
  const float* Wr   = (const float*)d_in[6];
  const float* br   = (const float*)d_in[7];
  const float* kl   = (const float*)d_in[8];
  float* out = (float*)d_out;

  float* ws_se = (float*)d_ws;
  float* ws_tg = ws_se + 2 * BT;

  if (ws_size >= WS_NEED) {
    unsigned short* bf = (unsigned short*)((char*)d_ws + WS_BF_BYTE);
    kto_convert<<<(CVT_TOTAL / 4096), 256, 0, stream>>>(X, Xr, W, Wr, bf, ws_se);
    kto_lse_gemm3<<<8000, 256, 0, stream>>>(bf, bias, br, tgt, ws_se, ws_tg);
  } else {
    kto_zero_ws<<<32, 256, 0, stream>>>(ws_se);
    dim3 grid(BT / 128, VDIM / 1280, 2);
    kto_lse_gemm_slow<<<grid, 256, 0, stream>>>(X, W, bias, Xr, Wr, br, tgt, ws_se, ws_tg);
  }

  kto_finalize<<<1, 256, 0, stream>>>(ws_se, ws_tg, tgt, pref, kl, out);
}